// Round 1
// baseline (1077.339 us; speedup 1.0000x reference)
//
#include <hip/hip_runtime.h>
#include <hip/hip_bf16.h>
#include <stdint.h>

typedef __hip_bfloat16 bf16;
typedef __attribute__((ext_vector_type(8))) __bf16 bf16x8;
typedef __attribute__((ext_vector_type(8))) unsigned short ushort8;
typedef __attribute__((ext_vector_type(4))) float floatx4;

#define MFMA_16x16x32(a, b, c) __builtin_amdgcn_mfma_f32_16x16x32_bf16((a), (b), (c), 0, 0, 0)

// async global->LDS, 16B per lane. LDS dest = wave-uniform base + lane*16.
__device__ __forceinline__ void async_load16(const bf16* g, bf16* l) {
  __builtin_amdgcn_global_load_lds(
      (const __attribute__((address_space(1))) unsigned int*)g,
      (__attribute__((address_space(3))) unsigned int*)l,
      16, 0, 0);
}

// ---------------------------------------------------------------------------
// fp32 -> bf16 cast, 8 elems/thread
// ---------------------------------------------------------------------------
__global__ __launch_bounds__(256)
void f32_to_bf16_k(const float* __restrict__ in, bf16* __restrict__ out, int n)
{
  const int i = (blockIdx.x * 256 + threadIdx.x) * 8;
  if (i >= n) return;
  bf16 tmp[8];
#pragma unroll
  for (int j = 0; j < 8; ++j) tmp[j] = __float2bfloat16(in[i + j]);
  *(ushort8*)&out[i] = *(const ushort8*)tmp;
}

// ---------------------------------------------------------------------------
// C[M,N] = A[M,K] @ B[N,K]^T   (bf16 in, fp32 acc, bf16 or fp32 out)
// m97 structure: 128x128 tile, 4 waves 2x2, 4x4 16x16x32 MFMA per wave, BK=32
// ---------------------------------------------------------------------------
__global__ __launch_bounds__(256, 2)
void gemm_bt(const bf16* __restrict__ A, const bf16* __restrict__ B,
             bf16* __restrict__ Cb, float* __restrict__ Cf,
             int M, int N, int K)
{
  __shared__ bf16 sA[128 * 32];
  __shared__ bf16 sB[128 * 32];

  const int tid  = threadIdx.x;
  const int lane = tid & 63;
  const int w    = tid >> 6;
  const int wm   = w >> 1;
  const int wn   = w & 1;
  const int quad = lane >> 4;
  const int l16  = lane & 15;
  const int tileM = blockIdx.y * 128;
  const int tileN = blockIdx.x * 128;

  floatx4 acc[4][4];
#pragma unroll
  for (int i = 0; i < 4; ++i)
#pragma unroll
    for (int j = 0; j < 4; ++j) acc[i][j] = (floatx4){0.f, 0.f, 0.f, 0.f};

  for (int k0 = 0; k0 < K; k0 += 32) {
    __syncthreads();  // previous iter's frag reads done before overwrite
#pragma unroll
    for (int s = 0; s < 2; ++s) {
      const int cid = (w * 2 + s) * 64 + lane;   // 16B chunk id, 512 total
      const int row = cid >> 2;                  // 4 chunks per 32-elem row
      const int col = (cid & 3) << 3;
      async_load16(A + (size_t)(tileM + row) * K + k0 + col, &sA[(w * 2 + s) * 64 * 8]);
      async_load16(B + (size_t)(tileN + row) * K + k0 + col, &sB[(w * 2 + s) * 64 * 8]);
    }
    __syncthreads();  // drains vmcnt(0): staging complete

    bf16x8 af[4], bfr[4];
#pragma unroll
    for (int i = 0; i < 4; ++i)
      af[i] = *(const bf16x8*)&sA[(wm * 64 + i * 16 + l16) * 32 + quad * 8];
#pragma unroll
    for (int j = 0; j < 4; ++j)
      bfr[j] = *(const bf16x8*)&sB[(wn * 64 + j * 16 + l16) * 32 + quad * 8];
#pragma unroll
    for (int i = 0; i < 4; ++i)
#pragma unroll
      for (int j = 0; j < 4; ++j)
        acc[i][j] = MFMA_16x16x32(af[i], bfr[j], acc[i][j]);
  }

  // epilogue: C/D layout col=lane&15, row=quad*4+reg (m89-verified)
#pragma unroll
  for (int i = 0; i < 4; ++i)
#pragma unroll
    for (int j = 0; j < 4; ++j)
#pragma unroll
      for (int r = 0; r < 4; ++r) {
        const int row = tileM + wm * 64 + i * 16 + quad * 4 + r;
        const int col = tileN + wn * 64 + j * 16 + l16;
        if (Cf) Cf[(size_t)row * N + col] = acc[i][j][r];
        else    Cb[(size_t)row * N + col] = __float2bfloat16(acc[i][j][r]);
      }
}

// ---------------------------------------------------------------------------
// V transpose: qkv[b*T+t, 4096 + h*128 + dim] -> Vt[(bh*128 + dim)*2048 + t]
// ---------------------------------------------------------------------------
__global__ __launch_bounds__(256)
void transpose_v(const bf16* __restrict__ qkv, bf16* __restrict__ Vt)
{
  __shared__ bf16 tile[64 * 128];
  const int t0 = blockIdx.x * 64;
  const int bh = blockIdx.y;
  const int b = bh >> 4;
  const int h = bh & 15;
  const int tid = threadIdx.x;
  const bf16* src = qkv + (size_t)(b * 2048 + t0) * 6144 + 4096 + h * 128;
#pragma unroll
  for (int s = 0; s < 4; ++s) {
    const int cid = s * 256 + tid;
    const int row = cid >> 4;
    const int col = (cid & 15) << 3;
    *(ushort8*)&tile[row * 128 + col] = *(const ushort8*)&src[(size_t)row * 6144 + col];
  }
  __syncthreads();
  const int dim = tid >> 1;
  const int tp  = (tid & 1) << 5;
  bf16 vals[32];
#pragma unroll
  for (int t = 0; t < 32; ++t) vals[t] = tile[(tp + t) * 128 + dim];
  bf16* dst = Vt + (size_t)(bh * 128 + dim) * 2048 + t0 + tp;
#pragma unroll
  for (int s = 0; s < 4; ++s) *(ushort8*)&dst[s * 8] = ((const ushort8*)vals)[s];
}

// ---------------------------------------------------------------------------
// Flash attention, causal. One block per (q-tile of 64, b*h).
// 4 waves; wave w owns q-rows w*16..w*16+15. BKV=64 key blocks.
// ---------------------------------------------------------------------------
__global__ __launch_bounds__(256, 2)
void flash_attn(const bf16* __restrict__ qkv, const bf16* __restrict__ Vt,
                bf16* __restrict__ outb)
{
  __shared__ bf16 sQ[64 * 128];   // [qrow][d]
  __shared__ bf16 sK[64 * 128];   // [key][d]
  __shared__ bf16 sV[128 * 64];   // [d][key]  (transposed)
  __shared__ bf16 sP[4][16 * 64]; // per-wave P round-trip (C-layout -> A-layout)

  const int qb  = blockIdx.x;   // 0..31
  const int bh  = blockIdx.y;   // 0..63
  const int b   = bh >> 4;
  const int h   = bh & 15;
  const int tid = threadIdx.x;
  const int lane = tid & 63;
  const int w    = tid >> 6;
  const int quad = lane >> 4;
  const int l16  = lane & 15;

  const size_t rs = 6144;
  const bf16* Qg = qkv + (size_t)(b * 2048 + qb * 64) * rs + h * 128;
  const bf16* Kg = qkv + (size_t)(b * 2048) * rs + 2048 + h * 128;
  const bf16* Vg = Vt + (size_t)bh * 128 * 2048;

  // stage Q once (64x128 bf16 = 16KB = 16 wave-issues)
#pragma unroll
  for (int s = 0; s < 4; ++s) {
    const int cid = (w * 4 + s) * 64 + lane;
    const int row = cid >> 4;
    const int col = (cid & 15) << 3;
    async_load16(Qg + (size_t)row * rs + col, &sQ[(w * 4 + s) * 64 * 8]);
  }

  floatx4 o[8];
#pragma unroll
  for (int s = 0; s < 8; ++s) o[s] = (floatx4){0.f, 0.f, 0.f, 0.f};
  float m_i[4], l_i[4];
#pragma unroll
  for (int r = 0; r < 4; ++r) { m_i[r] = -__builtin_inff(); l_i[r] = 0.f; }

  const float csc = 1.4426950408889634f * 0.08838834764831845f; // log2(e)/sqrt(128)

  for (int kb = 0; kb <= qb; ++kb) {
    __syncthreads();  // protect sK/sV from previous iteration's readers
#pragma unroll
    for (int s = 0; s < 4; ++s) {
      const int cid = (w * 4 + s) * 64 + lane;
      { const int row = cid >> 4; const int col = (cid & 15) << 3;
        async_load16(Kg + (size_t)(kb * 64 + row) * rs + col, &sK[(w * 4 + s) * 64 * 8]); }
      { const int row = cid >> 3; const int col = (cid & 7) << 3;
        async_load16(Vg + (size_t)row * 2048 + kb * 64 + col, &sV[(w * 4 + s) * 64 * 8]); }
    }
    __syncthreads();  // staging (incl. Q on first iter) drained

    // S = Q_w(16x128) @ K_tile^T(128x64): 4 key-subtiles x 4 d-chunks
    floatx4 sacc[4];
#pragma unroll
    for (int j = 0; j < 4; ++j) sacc[j] = (floatx4){0.f, 0.f, 0.f, 0.f};
#pragma unroll
    for (int kc = 0; kc < 4; ++kc) {
      const bf16x8 aq = *(const bf16x8*)&sQ[(w * 16 + l16) * 128 + kc * 32 + quad * 8];
#pragma unroll
      for (int j = 0; j < 4; ++j) {
        const bf16x8 bk = *(const bf16x8*)&sK[(j * 16 + l16) * 128 + kc * 32 + quad * 8];
        sacc[j] = MFMA_16x16x32(aq, bk, sacc[j]);
      }
    }

    // scale + causal mask + online softmax (rows live in one 16-lane quad)
    float p[4][4], mx[4];
    const int qrow = qb * 64 + w * 16 + quad * 4;  // + r
    const int key0 = kb * 64 + l16;                // + j*16
#pragma unroll
    for (int r = 0; r < 4; ++r) mx[r] = -__builtin_inff();
#pragma unroll
    for (int j = 0; j < 4; ++j)
#pragma unroll
      for (int r = 0; r < 4; ++r) {
        float v = sacc[j][r] * csc;
        if (kb == qb && key0 + j * 16 > qrow + r) v = -__builtin_inff();
        p[j][r] = v;
        mx[r] = fmaxf(mx[r], v);
      }
#pragma unroll
    for (int off = 1; off < 16; off <<= 1)
#pragma unroll
      for (int r = 0; r < 4; ++r) mx[r] = fmaxf(mx[r], __shfl_xor(mx[r], off, 64));

    float alpha[4], rsum[4];
#pragma unroll
    for (int r = 0; r < 4; ++r) {
      const float mnew = fmaxf(m_i[r], mx[r]);
      alpha[r] = __builtin_amdgcn_exp2f(m_i[r] - mnew);
      m_i[r] = mnew;
      float rsl = 0.f;
#pragma unroll
      for (int j = 0; j < 4; ++j) {
        const float e = __builtin_amdgcn_exp2f(p[j][r] - mnew);
        p[j][r] = e;
        rsl += e;
      }
      rsum[r] = rsl;
    }
#pragma unroll
    for (int off = 1; off < 16; off <<= 1)
#pragma unroll
      for (int r = 0; r < 4; ++r) rsum[r] += __shfl_xor(rsum[r], off, 64);
#pragma unroll
    for (int r = 0; r < 4; ++r) l_i[r] = alpha[r] * l_i[r] + rsum[r];
#pragma unroll
    for (int s = 0; s < 8; ++s)
#pragma unroll
      for (int r = 0; r < 4; ++r) o[s][r] *= alpha[r];

    // P: C-layout regs -> LDS -> A-layout frags (per-wave region, no barrier)
#pragma unroll
    for (int j = 0; j < 4; ++j)
#pragma unroll
      for (int r = 0; r < 4; ++r)
        sP[w][(quad * 4 + r) * 64 + j * 16 + l16] = __float2bfloat16(p[j][r]);

    // O += P(16x64) @ V(64x128)
#pragma unroll
    for (int kc = 0; kc < 2; ++kc) {
      const bf16x8 ap = *(const bf16x8*)&sP[w][l16 * 64 + kc * 32 + quad * 8];
#pragma unroll
      for (int s = 0; s < 8; ++s) {
        const bf16x8 bv = *(const bf16x8*)&sV[(s * 16 + l16) * 64 + kc * 32 + quad * 8];
        o[s] = MFMA_16x16x32(ap, bv, o[s]);
      }
    }
  }

  // epilogue: O /= l, write bf16 to [b*T + q, h*128 + dim]
  float rl[4];
#pragma unroll
  for (int r = 0; r < 4; ++r) rl[r] = 1.f / l_i[r];
  bf16* dst = outb + (size_t)(b * 2048 + qb * 64 + w * 16) * 2048 + h * 128;
#pragma unroll
  for (int s = 0; s < 8; ++s)
#pragma unroll
    for (int r = 0; r < 4; ++r)
      dst[(size_t)(quad * 4 + r) * 2048 + s * 16 + l16] = __float2bfloat16(o[s][r] * rl[r]);
}

// ---------------------------------------------------------------------------
extern "C" void kernel_launch(void* const* d_in, const int* in_sizes, int n_in,
                              void* d_out, int out_size, void* d_ws, size_t ws_size,
                              hipStream_t stream)
{
  (void)in_sizes; (void)n_in; (void)out_size; (void)ws_size;
  const float* x  = (const float*)d_in[0];   // [4,2048,2048]
  const float* Wa = (const float*)d_in[1];   // [6144,2048]
  const float* Wp = (const float*)d_in[2];   // [2048,2048]
  float* out = (float*)d_out;                // [4,2048,2048] fp32
  char* ws = (char*)d_ws;

  // workspace layout (bytes)
  bf16* xb   = (bf16*)(ws + 0);              //  33,554,432  x bf16 (dead after GEMM1)
  bf16* Wab  = (bf16*)(ws + 33554432ull);    //  25,165,824  W_attn bf16
  bf16* Wpb  = (bf16*)(ws + 58720256ull);    //   8,388,608  W_proj bf16
  bf16* qkv  = (bf16*)(ws + 67108864ull);    // 100,663,296  [8192,6144] bf16
  bf16* attb = (bf16*)(ws + 167772160ull);   //  33,554,432  attn out bf16
  bf16* Vt   = xb;                           // alias: V transposed [64][128][2048]

  f32_to_bf16_k<<<8192, 256, 0, stream>>>(x,  xb,  4 * 2048 * 2048);
  f32_to_bf16_k<<<6144, 256, 0, stream>>>(Wa, Wab, 3 * 2048 * 2048);
  f32_to_bf16_k<<<2048, 256, 0, stream>>>(Wp, Wpb, 2048 * 2048);

  // qkv = x @ W_attn^T   [8192,6144]
  gemm_bt<<<dim3(48, 64), 256, 0, stream>>>(xb, Wab, qkv, nullptr, 8192, 6144, 2048);
  // Vt[bh][d][t]
  transpose_v<<<dim3(32, 64), 256, 0, stream>>>(qkv, Vt);
  // attention
  flash_attn<<<dim3(32, 64), 256, 0, stream>>>(qkv, Vt, attb);
  // out = attb @ W_proj^T  [8192,2048] fp32
  gemm_bt<<<dim3(16, 64), 256, 0, stream>>>(attb, Wpb, nullptr, out, 8192, 2048, 2048);
}

// Round 2
// 774.239 us; speedup vs baseline: 1.3915x; 1.3915x over previous
//
#include <hip/hip_runtime.h>
#include <hip/hip_bf16.h>
#include <stdint.h>

typedef __hip_bfloat16 bf16;
typedef __attribute__((ext_vector_type(8))) __bf16 bf16x8;
typedef __attribute__((ext_vector_type(8))) unsigned short ushort8;
typedef __attribute__((ext_vector_type(4))) float floatx4;

#define MFMA_16x16x32(a, b, c) __builtin_amdgcn_mfma_f32_16x16x32_bf16((a), (b), (c), 0, 0, 0)

// async global->LDS, 16B per lane. LDS dest = wave-uniform base + lane*16.
// Global side is per-lane addressed -> we can swizzle the SOURCE chunk.
__device__ __forceinline__ void async_load16(const bf16* g, bf16* l) {
  __builtin_amdgcn_global_load_lds(
      (const __attribute__((address_space(1))) unsigned int*)g,
      (__attribute__((address_space(3))) unsigned int*)l,
      16, 0, 0);
}

// ---------------------------------------------------------------------------
// fp32 -> bf16 cast, 8 elems/thread
// ---------------------------------------------------------------------------
__global__ __launch_bounds__(256)
void f32_to_bf16_k(const float* __restrict__ in, bf16* __restrict__ out, int n)
{
  const int i = (blockIdx.x * 256 + threadIdx.x) * 8;
  if (i >= n) return;
  bf16 tmp[8];
#pragma unroll
  for (int j = 0; j < 8; ++j) tmp[j] = __float2bfloat16(in[i + j]);
  *(ushort8*)&out[i] = *(const ushort8*)tmp;
}

// ---------------------------------------------------------------------------
// C[M,N] = A[M,K] @ B[N,K]^T   (bf16 in, fp32 acc, bf16 or fp32 out)
// m97 structure + XOR chunk swizzle: row of 32 elems = 4 chunks of 16B;
// LDS slot c of row r holds global chunk c ^ mask(r), mask(r)=(r&3)^((r>>2)&3).
// Frag read for (row, quad) reads slot quad ^ mask(row) -> 2-way conflicts.
// ---------------------------------------------------------------------------
__global__ __launch_bounds__(256, 2)
void gemm_bt(const bf16* __restrict__ A, const bf16* __restrict__ B,
             bf16* __restrict__ Cb, float* __restrict__ Cf,
             int M, int N, int K)
{
  __shared__ bf16 sA[128 * 32];
  __shared__ bf16 sB[128 * 32];

  const int tid  = threadIdx.x;
  const int lane = tid & 63;
  const int w    = tid >> 6;
  const int wm   = w >> 1;
  const int wn   = w & 1;
  const int quad = lane >> 4;
  const int l16  = lane & 15;
  const int tileM = blockIdx.y * 128;
  const int tileN = blockIdx.x * 128;
  const int rmask = (l16 & 3) ^ ((l16 >> 2) & 3);  // frag-read swizzle mask

  floatx4 acc[4][4];
#pragma unroll
  for (int i = 0; i < 4; ++i)
#pragma unroll
    for (int j = 0; j < 4; ++j) acc[i][j] = (floatx4){0.f, 0.f, 0.f, 0.f};

  // staging swizzle (computed once): cid -> row, swizzled source column
  int st_row[2], st_col[2];
#pragma unroll
  for (int s = 0; s < 2; ++s) {
    const int cid = (w * 2 + s) * 64 + lane;
    const int row = cid >> 2;
    st_row[s] = row;
    st_col[s] = ((cid & 3) ^ ((row & 3) ^ ((row >> 2) & 3))) << 3;
  }

  for (int k0 = 0; k0 < K; k0 += 32) {
    __syncthreads();
#pragma unroll
    for (int s = 0; s < 2; ++s) {
      async_load16(A + (size_t)(tileM + st_row[s]) * K + k0 + st_col[s], &sA[(w * 2 + s) * 64 * 8]);
      async_load16(B + (size_t)(tileN + st_row[s]) * K + k0 + st_col[s], &sB[(w * 2 + s) * 64 * 8]);
    }
    __syncthreads();

    bf16x8 af[4], bfr[4];
#pragma unroll
    for (int i = 0; i < 4; ++i)
      af[i] = *(const bf16x8*)&sA[(wm * 64 + i * 16 + l16) * 32 + (quad ^ rmask) * 8];
#pragma unroll
    for (int j = 0; j < 4; ++j)
      bfr[j] = *(const bf16x8*)&sB[(wn * 64 + j * 16 + l16) * 32 + (quad ^ rmask) * 8];
#pragma unroll
    for (int i = 0; i < 4; ++i)
#pragma unroll
      for (int j = 0; j < 4; ++j)
        acc[i][j] = MFMA_16x16x32(af[i], bfr[j], acc[i][j]);
  }

  // epilogue: C/D layout col=lane&15, row=quad*4+reg (m89-verified)
#pragma unroll
  for (int i = 0; i < 4; ++i)
#pragma unroll
    for (int j = 0; j < 4; ++j)
#pragma unroll
      for (int r = 0; r < 4; ++r) {
        const int row = tileM + wm * 64 + i * 16 + quad * 4 + r;
        const int col = tileN + wn * 64 + j * 16 + l16;
        if (Cf) Cf[(size_t)row * N + col] = acc[i][j][r];
        else    Cb[(size_t)row * N + col] = __float2bfloat16(acc[i][j][r]);
      }
}

// ---------------------------------------------------------------------------
// V transpose: qkv[b*T+t, 4096 + h*128 + dim] -> Vt[(bh*128 + dim)*2048 + t]
// ---------------------------------------------------------------------------
__global__ __launch_bounds__(256)
void transpose_v(const bf16* __restrict__ qkv, bf16* __restrict__ Vt)
{
  __shared__ bf16 tile[64 * 128];
  const int t0 = blockIdx.x * 64;
  const int bh = blockIdx.y;
  const int b = bh >> 4;
  const int h = bh & 15;
  const int tid = threadIdx.x;
  const bf16* src = qkv + (size_t)(b * 2048 + t0) * 6144 + 4096 + h * 128;
#pragma unroll
  for (int s = 0; s < 4; ++s) {
    const int cid = s * 256 + tid;
    const int row = cid >> 4;
    const int col = (cid & 15) << 3;
    *(ushort8*)&tile[row * 128 + col] = *(const ushort8*)&src[(size_t)row * 6144 + col];
  }
  __syncthreads();
  const int dim = tid >> 1;
  const int tp  = (tid & 1) << 5;
  bf16 vals[32];
#pragma unroll
  for (int t = 0; t < 32; ++t) vals[t] = tile[(tp + t) * 128 + dim];
  bf16* dst = Vt + (size_t)(bh * 128 + dim) * 2048 + t0 + tp;
#pragma unroll
  for (int s = 0; s < 4; ++s) *(ushort8*)&dst[s * 8] = ((const ushort8*)vals)[s];
}

// ---------------------------------------------------------------------------
// Flash attention, causal. One block per (q-tile of 64, b*h).
// All LDS tiles XOR-chunk-swizzled: 16-way bank conflicts -> 2-way (free).
//   sQ/sK: 16 chunks/row, mask = row&15 (== l16 at read time)
//   sV   :  8 chunks/row, mask = row&7
//   sP   : padded to 72 elems/row
// ---------------------------------------------------------------------------
__global__ __launch_bounds__(256, 2)
void flash_attn(const bf16* __restrict__ qkv, const bf16* __restrict__ Vt,
                bf16* __restrict__ outb)
{
  __shared__ bf16 sQ[64 * 128];   // [qrow][d]   swizzled
  __shared__ bf16 sK[64 * 128];   // [key][d]    swizzled
  __shared__ bf16 sV[128 * 64];   // [d][key]    swizzled
  __shared__ bf16 sP[4][16 * 72]; // per-wave, padded

  const int qb  = gridDim.x - 1 - blockIdx.x;  // heavy tiles dispatch first
  const int bh  = blockIdx.y;   // 0..63
  const int b   = bh >> 4;
  const int h   = bh & 15;
  const int tid = threadIdx.x;
  const int lane = tid & 63;
  const int w    = tid >> 6;
  const int quad = lane >> 4;
  const int l16  = lane & 15;

  const size_t rs = 6144;
  const bf16* Qg = qkv + (size_t)(b * 2048 + qb * 64) * rs + h * 128;
  const bf16* Kg = qkv + (size_t)(b * 2048) * rs + 2048 + h * 128;
  const bf16* Vg = Vt + (size_t)bh * 128 * 2048;

  // staging index precompute (per lane, loop-invariant)
  int qk_row[4], qk_col[4], v_row[4], v_col[4];
#pragma unroll
  for (int s = 0; s < 4; ++s) {
    const int cid = (w * 4 + s) * 64 + lane;
    qk_row[s] = cid >> 4;                               // 16 chunks/row
    qk_col[s] = ((cid & 15) ^ (qk_row[s] & 15)) << 3;
    v_row[s]  = cid >> 3;                               // 8 chunks/row
    v_col[s]  = ((cid & 7) ^ (v_row[s] & 7)) << 3;
  }

  // stage Q once (swizzled)
#pragma unroll
  for (int s = 0; s < 4; ++s)
    async_load16(Qg + (size_t)qk_row[s] * rs + qk_col[s], &sQ[(w * 4 + s) * 64 * 8]);

  floatx4 o[8];
#pragma unroll
  for (int s = 0; s < 8; ++s) o[s] = (floatx4){0.f, 0.f, 0.f, 0.f};
  float m_i[4], l_i[4];
#pragma unroll
  for (int r = 0; r < 4; ++r) { m_i[r] = -__builtin_inff(); l_i[r] = 0.f; }

  const float csc = 1.4426950408889634f * 0.08838834764831845f; // log2(e)/sqrt(128)

  for (int kb = 0; kb <= qb; ++kb) {
    __syncthreads();  // prev iter's frag reads done before overwrite
#pragma unroll
    for (int s = 0; s < 4; ++s) {
      async_load16(Kg + (size_t)(kb * 64 + qk_row[s]) * rs + qk_col[s], &sK[(w * 4 + s) * 64 * 8]);
      async_load16(Vg + (size_t)v_row[s] * 2048 + kb * 64 + v_col[s],   &sV[(w * 4 + s) * 64 * 8]);
    }
    __syncthreads();  // staging drained (vmcnt(0) before s_barrier)

    // S = Q_w(16x128) @ K_tile^T(128x64); swizzled chunk = (kc*4+quad)^l16
    floatx4 sacc[4];
#pragma unroll
    for (int j = 0; j < 4; ++j) sacc[j] = (floatx4){0.f, 0.f, 0.f, 0.f};
#pragma unroll
    for (int kc = 0; kc < 4; ++kc) {
      const int ch = ((kc * 4 + quad) ^ l16) * 8;
      const bf16x8 aq = *(const bf16x8*)&sQ[(w * 16 + l16) * 128 + ch];
#pragma unroll
      for (int j = 0; j < 4; ++j) {
        const bf16x8 bk = *(const bf16x8*)&sK[(j * 16 + l16) * 128 + ch];
        sacc[j] = MFMA_16x16x32(aq, bk, sacc[j]);
      }
    }

    // scale + causal mask + online softmax (rows live in one 16-lane quad)
    float p[4][4], mx[4];
    const int qrow = qb * 64 + w * 16 + quad * 4;  // + r
    const int key0 = kb * 64 + l16;                // + j*16
#pragma unroll
    for (int r = 0; r < 4; ++r) mx[r] = -__builtin_inff();
#pragma unroll
    for (int j = 0; j < 4; ++j)
#pragma unroll
      for (int r = 0; r < 4; ++r) {
        float v = sacc[j][r] * csc;
        if (kb == qb && key0 + j * 16 > qrow + r) v = -__builtin_inff();
        p[j][r] = v;
        mx[r] = fmaxf(mx[r], v);
      }
#pragma unroll
    for (int off = 1; off < 16; off <<= 1)
#pragma unroll
      for (int r = 0; r < 4; ++r) mx[r] = fmaxf(mx[r], __shfl_xor(mx[r], off, 64));

    float alpha[4], rsum[4];
#pragma unroll
    for (int r = 0; r < 4; ++r) {
      const float mnew = fmaxf(m_i[r], mx[r]);
      alpha[r] = __builtin_amdgcn_exp2f(m_i[r] - mnew);
      m_i[r] = mnew;
      float rsl = 0.f;
#pragma unroll
      for (int j = 0; j < 4; ++j) {
        const float e = __builtin_amdgcn_exp2f(p[j][r] - mnew);
        p[j][r] = e;
        rsl += e;
      }
      rsum[r] = rsl;
    }
#pragma unroll
    for (int off = 1; off < 16; off <<= 1)
#pragma unroll
      for (int r = 0; r < 4; ++r) rsum[r] += __shfl_xor(rsum[r], off, 64);
#pragma unroll
    for (int r = 0; r < 4; ++r) l_i[r] = alpha[r] * l_i[r] + rsum[r];
#pragma unroll
    for (int s = 0; s < 8; ++s)
#pragma unroll
      for (int r = 0; r < 4; ++r) o[s][r] *= alpha[r];

    // P: C-layout regs -> LDS (padded) -> A-layout frags (per-wave, no barrier)
#pragma unroll
    for (int j = 0; j < 4; ++j)
#pragma unroll
      for (int r = 0; r < 4; ++r)
        sP[w][(quad * 4 + r) * 72 + j * 16 + l16] = __float2bfloat16(p[j][r]);

    // O += P(16x64) @ V(64x128); sV swizzled chunk = (kc*4+quad)^(l16&7)
#pragma unroll
    for (int kc = 0; kc < 2; ++kc) {
      const bf16x8 ap = *(const bf16x8*)&sP[w][l16 * 72 + kc * 32 + quad * 8];
      const int chv = ((kc * 4 + quad) ^ (l16 & 7)) * 8;
#pragma unroll
      for (int s = 0; s < 8; ++s) {
        const bf16x8 bv = *(const bf16x8*)&sV[(s * 16 + l16) * 64 + chv];
        o[s] = MFMA_16x16x32(ap, bv, o[s]);
      }
    }
  }

  // epilogue: O /= l, write bf16 to [b*T + q, h*128 + dim]
  float rl[4];
#pragma unroll
  for (int r = 0; r < 4; ++r) rl[r] = 1.f / l_i[r];
  bf16* dst = outb + (size_t)(b * 2048 + qb * 64 + w * 16) * 2048 + h * 128;
#pragma unroll
  for (int s = 0; s < 8; ++s)
#pragma unroll
    for (int r = 0; r < 4; ++r)
      dst[(size_t)(quad * 4 + r) * 2048 + s * 16 + l16] = __float2bfloat16(o[s][r] * rl[r]);
}

// ---------------------------------------------------------------------------
extern "C" void kernel_launch(void* const* d_in, const int* in_sizes, int n_in,
                              void* d_out, int out_size, void* d_ws, size_t ws_size,
                              hipStream_t stream)
{
  (void)in_sizes; (void)n_in; (void)out_size; (void)ws_size;
  const float* x  = (const float*)d_in[0];   // [4,2048,2048]
  const float* Wa = (const float*)d_in[1];   // [6144,2048]
  const float* Wp = (const float*)d_in[2];   // [2048,2048]
  float* out = (float*)d_out;                // [4,2048,2048] fp32
  char* ws = (char*)d_ws;

  // workspace layout (bytes)
  bf16* xb   = (bf16*)(ws + 0);              //  33,554,432  x bf16 (dead after GEMM1)
  bf16* Wab  = (bf16*)(ws + 33554432ull);    //  25,165,824  W_attn bf16
  bf16* Wpb  = (bf16*)(ws + 58720256ull);    //   8,388,608  W_proj bf16
  bf16* qkv  = (bf16*)(ws + 67108864ull);    // 100,663,296  [8192,6144] bf16
  bf16* attb = (bf16*)(ws + 167772160ull);   //  33,554,432  attn out bf16
  bf16* Vt   = xb;                           // alias: V transposed [64][128][2048]

  f32_to_bf16_k<<<8192, 256, 0, stream>>>(x,  xb,  4 * 2048 * 2048);
  f32_to_bf16_k<<<6144, 256, 0, stream>>>(Wa, Wab, 3 * 2048 * 2048);
  f32_to_bf16_k<<<2048, 256, 0, stream>>>(Wp, Wpb, 2048 * 2048);

  // qkv = x @ W_attn^T   [8192,6144]
  gemm_bt<<<dim3(48, 64), 256, 0, stream>>>(xb, Wab, qkv, nullptr, 8192, 6144, 2048);
  // Vt[bh][d][t]
  transpose_v<<<dim3(32, 64), 256, 0, stream>>>(qkv, Vt);
  // attention
  flash_attn<<<dim3(32, 64), 256, 0, stream>>>(qkv, Vt, attb);
  // out = attb @ W_proj^T  [8192,2048] fp32
  gemm_bt<<<dim3(16, 64), 256, 0, stream>>>(attb, Wpb, nullptr, out, 8192, 2048, 2048);
}